// Round 5
// baseline (181.163 us; speedup 1.0000x reference)
//
#include <hip/hip_runtime.h>
#include <hip/hip_bf16.h>

typedef __attribute__((ext_vector_type(8))) short short8;
typedef __attribute__((ext_vector_type(4))) float f32x4;

// __float2bfloat16 emits a single HW cvt op on gfx950 (R8: bit-trick regressed).
__device__ __forceinline__ unsigned short f2bf(float f) {
  union { __hip_bfloat16 h; unsigned short u; } cv;
  cv.h = __float2bfloat16(f);
  return cv.u;
}

__device__ __forceinline__ void gld16(const void* g, void* l) {
  __builtin_amdgcn_global_load_lds(
      (const __attribute__((address_space(1))) unsigned int*)g,
      (__attribute__((address_space(3))) unsigned int*)l, 16, 0, 0);
}

__device__ __forceinline__ f32x4 mfma_bf16(short8 a, short8 b, f32x4 c) {
  return __builtin_amdgcn_mfma_f32_16x16x32_bf16(a, b, c, 0, 0, 0);
}

#define QSCALE 0.18033688011112042f  /* 0.125 * log2(e): scores in log2 domain */
#define L2E    1.4426950408889634f

// ---------------------------------------------------------------- prep ----
// One launch: blocks [0,4096) cast X fp32->bf16; blocks [4096,5120) transpose
// weights (first 768: w_attn 64-col strips; last 256: w_proj).
__global__ void prep(const float* __restrict__ x, unsigned short* __restrict__ xbf,
                     const float* __restrict__ wa, unsigned short* __restrict__ da,
                     const float* __restrict__ wp, unsigned short* __restrict__ dp) {
  __shared__ float tile[64][65];
  const int t = threadIdx.x;
  const int bid = blockIdx.x;
  if (bid < 4096) {
    int i = bid * 256 + t;
    float4 v = ((const float4*)x)[i];
    ushort4 o;
    o.x = f2bf(v.x); o.y = f2bf(v.y); o.z = f2bf(v.z); o.w = f2bf(v.w);
    ((ushort4*)xbf)[i] = o;
    return;
  }
  int idx = bid - 4096;          // 0..1023
  const int tr = idx & 15;       // 16 row-strips of 64
  int y = idx >> 4;              // 0..63
  const float* src;
  unsigned short* dst;
  int C;
  if (y < 48) { src = wa; dst = da; C = 3072; }
  else        { src = wp; dst = dp; C = 1024; y -= 48; }
  const int tc = y;  // block-uniform
#pragma unroll
  for (int i = 0; i < 16; ++i) {
    int id2 = t + i * 256;
    int lr = id2 >> 6, lc = id2 & 63;
    tile[lr][lc] = src[(size_t)(tr * 64 + lr) * C + tc * 64 + lc];
  }
  __syncthreads();
#pragma unroll
  for (int i = 0; i < 16; ++i) {
    int id2 = t + i * 256;
    int lr = id2 >> 6, lc = id2 & 63;
    dst[(size_t)(tc * 64 + lr) * 1024 + tr * 64 + lc] = f2bf(tile[lc][lr]);
  }
}

// ---------------------------------------------------------------- GEMM ----
template <int KDIM>
__device__ __forceinline__ void gemm_core(const short* __restrict__ A, const short* __restrict__ Bt,
                                          int mbase, int nbase, short* As, short* Bs,
                                          int wm, int wn, int quad, int l16, int t,
                                          f32x4 (&acc)[4][4]) {
  for (int kt = 0; kt < KDIM / 32; ++kt) {
#pragma unroll
    for (int i = 0; i < 2; ++i) {
      int c = t + i * 256;
      int row = c >> 2, c4 = c & 3;
      gld16(A + (size_t)(mbase + row) * KDIM + kt * 32 + c4 * 8, (char*)As + c * 16);
      gld16(Bt + (size_t)(nbase + row) * KDIM + kt * 32 + c4 * 8, (char*)Bs + c * 16);
    }
    __syncthreads();
    short8 af[4], bf[4];
#pragma unroll
    for (int m = 0; m < 4; ++m)
      af[m] = *(const short8*)((const char*)As + (wm + m * 16 + l16) * 64 + quad * 16);
#pragma unroll
    for (int n = 0; n < 4; ++n)
      bf[n] = *(const short8*)((const char*)Bs + (wn + n * 16 + l16) * 64 + quad * 16);
#pragma unroll
    for (int m = 0; m < 4; ++m)
#pragma unroll
      for (int n = 0; n < 4; ++n)
        acc[m][n] = mfma_bf16(af[m], bf[n], acc[m][n]);
    __syncthreads();
  }
}

// Unified QKV GEMM: grid (32, 24) = 768 blocks (3/CU). nbase<2048 -> Q/K scatter
// (Q pre-scaled by QSCALE for log2-domain flash); nbase>=2048 -> V path with
// LDS-transpose epilogue emitting V' tau64-permuted [bh][d][2048]:
// stored pos (per 64-block) = 32*s5 + 8*((s>>2)&3) + 4*s4 + (s&3).
// tau64 matches flash's in-register P packing (swapped-QK S^T frags pack
// in-lane into PV A-operands with NO cross-lane moves).
__global__ __launch_bounds__(256, 2) void gemm_qkv(
    const short* __restrict__ A, const short* __restrict__ Bt, const float* __restrict__ bias,
    unsigned short* __restrict__ q, unsigned short* __restrict__ k,
    unsigned short* __restrict__ vt) {
  __shared__ __align__(16) char smem[17408];
  short* As = (short*)smem;
  short* Bs = (short*)(smem + 8192);
  unsigned short* vlds = (unsigned short*)smem;  // [64 d][136] permuted s (V epilogue)
  const int t = threadIdx.x;
  const int wave = t >> 6, lane = t & 63;
  const int quad = lane >> 4, l16 = lane & 15;
  const int wm = (wave >> 1) * 64, wn = (wave & 1) * 64;
  const int mbase = blockIdx.x * 128, nbase = blockIdx.y * 128;
  f32x4 acc[4][4];
#pragma unroll
  for (int i = 0; i < 4; ++i)
#pragma unroll
    for (int j = 0; j < 4; ++j) acc[i][j] = (f32x4)0.0f;
  gemm_core<1024>(A, Bt, mbase, nbase, As, Bs, wm, wn, quad, l16, t, acc);

  if (nbase < 2048) {
    // ---- Q/K scatter epilogue ----
#pragma unroll
    for (int n = 0; n < 4; ++n) {
      int col = nbase + wn + n * 16 + l16;      // 0..2047
      float bc = bias[col];
      int which = col >> 10, rem = col & 1023;  // wave-uniform per n
      int h = rem >> 6, d = rem & 63;
      unsigned short* dst = which ? k : q;
      float scale = which ? 1.0f : QSCALE;
#pragma unroll
      for (int m = 0; m < 4; ++m) {
#pragma unroll
        for (int r = 0; r < 4; ++r) {
          int row = mbase + wm + m * 16 + quad * 4 + r;
          int b = row >> 11, s = row & 2047;
          dst[(((size_t)(b * 16 + h)) * 2048 + s) * 64 + d] = f2bf((acc[m][n][r] + bc) * scale);
        }
      }
    }
  } else {
    // ---- V transpose epilogue: tau64 per 64-block ----
    const int b = mbase >> 11, s0 = mbase & 2047;
    const int vcb = nbase - 2048;  // 0..895, v-column base
    __syncthreads();               // hard fence before vlds reuses the GEMM stage region
#pragma unroll
    for (int half = 0; half < 2; ++half) {
      if (wn == half * 64) {
#pragma unroll
        for (int n = 0; n < 4; ++n) {
          int col_l = n * 16 + l16;  // d 0..63
          float bc = bias[nbase + half * 64 + col_l];
#pragma unroll
          for (int m = 0; m < 4; ++m)
#pragma unroll
            for (int r = 0; r < 4; ++r) {
              int row_l = wm + m * 16 + quad * 4 + r;  // s_local 0..127
              int idx = (row_l & 64) + ((row_l >> 5) & 1) * 32 +
                        ((row_l >> 2) & 3) * 8 + ((row_l >> 4) & 1) * 4 + (row_l & 3);
              vlds[col_l * 136 + idx] = f2bf(acc[m][n][r] + bc);
            }
        }
      }
      __syncthreads();
      int h = (vcb + half * 64) >> 6;  // head 0..15
      size_t obase = ((size_t)(b * 16 + h)) * 64 * 2048;
#pragma unroll
      for (int i = 0; i < 4; ++i) {
        int c = t + i * 256;
        int d_l = c >> 4, c16 = c & 15;
        short8 v = *(const short8*)&vlds[d_l * 136 + c16 * 8];
        *(short8*)&vt[obase + (size_t)d_l * 2048 + s0 + c16 * 8] = v;
      }
      __syncthreads();
    }
  }
}

// Proj: 64x128 tiles, grid (64,8) = 512 blocks (2/CU) — R8-proven correct+faster.
__global__ __launch_bounds__(256, 2) void gemm_proj(
    const short* __restrict__ A, const short* __restrict__ Bt, const float* __restrict__ bias,
    float* __restrict__ out) {
  __shared__ __align__(16) short As[64 * 32];
  __shared__ __align__(16) short Bs[128 * 32];
  const int t = threadIdx.x;
  const int wave = t >> 6, lane = t & 63;
  const int quad = lane >> 4, l16 = lane & 15;
  const int wm = (wave >> 1) * 32, wn = (wave & 1) * 64;
  const int mbase = blockIdx.x * 64, nbase = blockIdx.y * 128;
  f32x4 acc[2][4];
#pragma unroll
  for (int i = 0; i < 2; ++i)
#pragma unroll
    for (int j = 0; j < 4; ++j) acc[i][j] = (f32x4)0.0f;
  for (int kt = 0; kt < 32; ++kt) {
    {  // A: 64 rows x 4 chunks = 256 chunks, 1/thread
      int row = t >> 2, c4 = t & 3;
      gld16(A + (size_t)(mbase + row) * 1024 + kt * 32 + c4 * 8, (char*)As + t * 16);
    }
#pragma unroll
    for (int i = 0; i < 2; ++i) {  // B: 128 rows x 4 chunks = 512 chunks, 2/thread
      int c = t + i * 256;
      int row = c >> 2, c4 = c & 3;
      gld16(Bt + (size_t)(nbase + row) * 1024 + kt * 32 + c4 * 8, (char*)Bs + c * 16);
    }
    __syncthreads();
    short8 af[2], bf[4];
#pragma unroll
    for (int m = 0; m < 2; ++m)
      af[m] = *(const short8*)((const char*)As + (wm + m * 16 + l16) * 64 + quad * 16);
#pragma unroll
    for (int n = 0; n < 4; ++n)
      bf[n] = *(const short8*)((const char*)Bs + (wn + n * 16 + l16) * 64 + quad * 16);
#pragma unroll
    for (int m = 0; m < 2; ++m)
#pragma unroll
      for (int n = 0; n < 4; ++n)
        acc[m][n] = mfma_bf16(af[m], bf[n], acc[m][n]);
    __syncthreads();
  }
#pragma unroll
  for (int n = 0; n < 4; ++n) {
    int col = nbase + wn + n * 16 + l16;
    float bc = bias[col];
#pragma unroll
    for (int m = 0; m < 2; ++m)
#pragma unroll
      for (int r = 0; r < 4; ++r) {
        int row = mbase + wm + m * 16 + quad * 4 + r;
        out[(size_t)row * 1024 + col] = acc[m][n][r] + bc;
      }
  }
}

// ---------------------------------------------------------------- flash ----
// R15: address-free inner loop. R14 post-mortem: VALUBusy 40% (~20 us) was
// co-largest pipe with LDS; ~14 us of it was per-iteration address math
// (swizzle recompute, 64-bit staging addrs, buffer selects) + 32 v_movs of
// sa zero-init, all on the wave's serial path.
//  * #pragma unroll 2 on kt: (kt&1) compile-time -> Kc/Vc fold into ds_read
//    offset immediates. Zero VALU for buffer select.
//  * koff[ks][n]/voff[ks][db] swizzled byte offsets precomputed ONCE, live in
//    VGPRs across the loop.
//  * staging/mask addresses are incrementing pointers (+4096/+64/+64 shorts).
//  * sa init removed: ks=0 MFMA takes literal-zero accumulator.
// Everything else identical to R14 (swapped-QK in-register softmax, tau64 V',
// KVBLK=64 dbuf stage-ahead, 1 barrier/kt, LDS 32768, grid (32,16)).
__global__ __launch_bounds__(256, 2) void flash_attn(
    const short* __restrict__ Qg, const short* __restrict__ Kg, const short* __restrict__ Vtg,
    const float* __restrict__ mask, unsigned short* __restrict__ ctx) {
  __shared__ __align__(16) unsigned char smem[32768];
  // K: [0,16384) two 8K buffers; V: [16384,32768) two 8K buffers
  const int t = threadIdx.x;  // 0..255
  const int wave = t >> 6, lane = t & 63;
  const int quad = lane >> 4, l16 = lane & 15;
  const int bh = blockIdx.x, b = bh >> 4, h = bh & 15;
  const int qbase = blockIdx.y * 128;
  const size_t bh_off = (size_t)bh * 2048 * 64;

  // ---- Q stage (16 KB = K-dbuf region), then to registers ----
#pragma unroll
  for (int i = 0; i < 4; ++i) {
    int c = t + i * 256;
    int row = c >> 3, col = c & 7;
    gld16(Qg + bh_off + (size_t)(qbase + row) * 64 + (col ^ (row & 7)) * 8,
          (char*)smem + c * 16);
  }
  __syncthreads();
  short8 qf[2][2];  // [m-frag][ks]
#pragma unroll
  for (int mf = 0; mf < 2; ++mf)
#pragma unroll
    for (int ks = 0; ks < 2; ++ks) {
      int row = wave * 32 + mf * 16 + l16;
      qf[mf][ks] = *(const short8*)((const char*)smem +
                                    (row * 8 + ((ks * 4 + quad) ^ (l16 & 7))) * 16);
    }
  __syncthreads();  // all waves done reading Q before K staging reuses region

  // ---- loop-invariant LDS byte offsets (VGPR-resident) ----
  int koff[2][4];  // [ks][n]
#pragma unroll
  for (int ks = 0; ks < 2; ++ks)
#pragma unroll
    for (int n = 0; n < 4; ++n) {
      int row = n * 16 + l16;
      koff[ks][n] = (row * 8 + ((ks * 4 + quad) ^ (l16 & 7))) * 16;
    }
  int voff[2][4];  // [ks][db]
#pragma unroll
  for (int ks = 0; ks < 2; ++ks)
#pragma unroll
    for (int db = 0; db < 4; ++db) {
      int d = db * 16 + l16;
      voff[ks][db] = d * 128 + (((ks * 4 + quad) ^ (d & 7)) * 16);
    }

  // ---- staging source pointers (increment by constants each kt) ----
  const short* kgp[2];
  const short* vgp[2];
#pragma unroll
  for (int i = 0; i < 2; ++i) {
    int c = t + i * 256;
    int row = c >> 3, col = c & 7;
    kgp[i] = Kg + bh_off + (size_t)row * 64 + (col ^ (row & 7)) * 8;
    vgp[i] = Vtg + ((size_t)bh * 64 + row) * 2048 + (col ^ (row & 7)) * 8;
  }
  const float* mpt = mask + b * 2048 + quad * 4;

  auto stage_to = [&](char* kd, char* vd) {
#pragma unroll
    for (int i = 0; i < 2; ++i) {
      gld16(kgp[i], kd + (t + i * 256) * 16);
      gld16(vgp[i], vd + (t + i * 256) * 16);
    }
    kgp[0] += 4096; kgp[1] += 4096;  // 64 rows x 64 shorts
    vgp[0] += 64;   vgp[1] += 64;    // 64 shorts along s
  };

  f32x4 O[2][4];
  float l_part[2];
#pragma unroll
  for (int mf = 0; mf < 2; ++mf)
#pragma unroll
    for (int d = 0; d < 4; ++d) O[mf][d] = (f32x4)0.0f;
  l_part[0] = 0.0f;
  l_part[1] = 0.0f;

  // prologue: stage kt=0 into buf0 (only cold stall of the kernel)
  stage_to((char*)smem, (char*)smem + 16384);
  __syncthreads();

#pragma unroll 2
  for (int kt = 0; kt < 32; ++kt) {
    const char* Kc = (const char*)smem + (kt & 1) * 8192;          // folds (unroll 2)
    const char* Vc = (const char*)smem + 16384 + (kt & 1) * 8192;  // folds (unroll 2)

    // mask: float4 per n-frag at s = kt*64 + n*16 + quad*4 (16B aligned)
    float4 mq[4];
#pragma unroll
    for (int n = 0; n < 4; ++n) mq[n] = *(const float4*)(mpt + n * 16);
    mpt += 64;

    // stage-ahead: K/V tiles for kt+1 (drained at the end-of-iter barrier)
    if (kt < 31)
      stage_to((char*)smem + ((kt + 1) & 1) * 8192,
               (char*)smem + 16384 + ((kt + 1) & 1) * 8192);

    // ---- S^T = K @ Q^T (log2 domain); kf feeds BOTH m-frags ----
    f32x4 sa[2][4];
    __builtin_amdgcn_s_setprio(1);
#pragma unroll
    for (int n = 0; n < 4; ++n) {
      short8 kf = *(const short8*)(Kc + koff[0][n]);
      sa[0][n] = mfma_bf16(kf, qf[0][0], (f32x4)0.0f);
      sa[1][n] = mfma_bf16(kf, qf[1][0], (f32x4)0.0f);
    }
#pragma unroll
    for (int n = 0; n < 4; ++n) {
      short8 kf = *(const short8*)(Kc + koff[1][n]);
      sa[0][n] = mfma_bf16(kf, qf[0][1], sa[0][n]);
      sa[1][n] = mfma_bf16(kf, qf[1][1], sa[1][n]);
    }
    __builtin_amdgcn_s_setprio(0);

    // ---- softmax fully in-register: lane owns q=l16, k = n*16+quad*4+r ----
    // Pack straight into PV A-frags (contraction positions = tau64 order)
    short8 pa[2][2];
#pragma unroll
    for (int mf = 0; mf < 2; ++mf) {
      float rs = 0.0f;
#pragma unroll
      for (int n = 0; n < 4; ++n) {
#pragma unroll
        for (int r = 0; r < 4; ++r) {
          float p = __builtin_amdgcn_exp2f(__builtin_fmaf(mq[n][r], L2E, sa[mf][n][r]));
          rs += p;
          pa[mf][n >> 1][(n & 1) * 4 + r] = (short)f2bf(p);
        }
      }
      l_part[mf] += rs;
    }

    // ---- O += P @ V' (vf feeds BOTH m-frags) ----
    __builtin_amdgcn_s_setprio(1);
#pragma unroll
    for (int ks = 0; ks < 2; ++ks) {
#pragma unroll
      for (int db = 0; db < 4; ++db) {
        short8 vf = *(const short8*)(Vc + voff[ks][db]);
        O[0][db] = mfma_bf16(pa[0][ks], vf, O[0][db]);
        O[1][db] = mfma_bf16(pa[1][ks], vf, O[1][db]);
      }
    }
    __builtin_amdgcn_s_setprio(0);

    // one barrier/kt: buf[cur] reads done block-wide + kt+1 stage drained
    __syncthreads();
  }

  // ---- l reduce: sum over quads (lane bits 4,5), then transpose to O layout ----
  float lr[2];
#pragma unroll
  for (int mf = 0; mf < 2; ++mf) {
    float l = l_part[mf];
    l += __shfl_xor(l, 16);
    l += __shfl_xor(l, 32);
    lr[mf] = l;  // valid for q = l16 (all quads hold it)
  }
#pragma unroll
  for (int mf = 0; mf < 2; ++mf) {
#pragma unroll
    for (int r = 0; r < 4; ++r) {
      float lq = __shfl(lr[mf], quad * 4 + r);  // l for q-local = quad*4+r
      float inv = 1.0f / lq;
      int s = qbase + wave * 32 + mf * 16 + quad * 4 + r;
      size_t o = ((size_t)b * 2048 + s) * 1024 + h * 64;
#pragma unroll
      for (int db = 0; db < 4; ++db)
        ctx[o + db * 16 + l16] = f2bf(O[mf][db][r] * inv);
    }
  }
}

// ---------------------------------------------------------------- launch ----
extern "C" void kernel_launch(void* const* d_in, const int* in_sizes, int n_in,
                              void* d_out, int out_size, void* d_ws, size_t ws_size,
                              hipStream_t stream) {
  const float* x      = (const float*)d_in[0];
  const float* mask   = (const float*)d_in[1];
  const float* w_attn = (const float*)d_in[2];
  const float* b_attn = (const float*)d_in[3];
  const float* w_proj = (const float*)d_in[4];
  const float* b_proj = (const float*)d_in[5];
  float* out = (float*)d_out;

  char* ws = (char*)d_ws;
  const size_t MB = 1024 * 1024;
  short*          Xbf    = (short*)(ws);                     // 8 MB, reused as ctx
  short*          Wqkv_t = (short*)(ws + 8 * MB);            // 6 MB
  short*          Wprj_t = (short*)(ws + 14 * MB);           // 2 MB
  unsigned short* Qb     = (unsigned short*)(ws + 16 * MB);  // 8 MB
  unsigned short* Kb     = (unsigned short*)(ws + 24 * MB);  // 8 MB
  unsigned short* Vtb    = (unsigned short*)(ws + 32 * MB);  // 8 MB
  unsigned short* ctx    = (unsigned short*)Xbf;

  prep<<<5120, 256, 0, stream>>>(x, (unsigned short*)Xbf,
                                 w_attn, (unsigned short*)Wqkv_t,
                                 w_proj, (unsigned short*)Wprj_t);
  gemm_qkv<<<dim3(32, 24), 256, 0, stream>>>(Xbf, Wqkv_t, b_attn, Qb, Kb, Vtb);
  flash_attn<<<dim3(32, 16), 256, 0, stream>>>((const short*)Qb, (const short*)Kb,
                                               (const short*)Vtb, mask, ctx);
  gemm_proj<<<dim3(64, 8), 256, 0, stream>>>((const short*)ctx, Wprj_t, b_proj, out);
}

// Round 6
// 178.780 us; speedup vs baseline: 1.0133x; 1.0133x over previous
//
#include <hip/hip_runtime.h>
#include <hip/hip_bf16.h>

typedef __attribute__((ext_vector_type(8))) short short8;
typedef __attribute__((ext_vector_type(4))) float f32x4;

// __float2bfloat16 emits a single HW cvt op on gfx950 (R8: bit-trick regressed).
__device__ __forceinline__ unsigned short f2bf(float f) {
  union { __hip_bfloat16 h; unsigned short u; } cv;
  cv.h = __float2bfloat16(f);
  return cv.u;
}

__device__ __forceinline__ void gld16(const void* g, void* l) {
  __builtin_amdgcn_global_load_lds(
      (const __attribute__((address_space(1))) unsigned int*)g,
      (__attribute__((address_space(3))) unsigned int*)l, 16, 0, 0);
}

__device__ __forceinline__ f32x4 mfma_bf16(short8 a, short8 b, f32x4 c) {
  return __builtin_amdgcn_mfma_f32_16x16x32_bf16(a, b, c, 0, 0, 0);
}

#define QSCALE 0.18033688011112042f  /* 0.125 * log2(e): scores in log2 domain */
#define L2E    1.4426950408889634f

// ---------------------------------------------------------------- prep ----
// One launch: blocks [0,4096) cast X fp32->bf16; blocks [4096,5120) transpose
// weights (first 768: w_attn 64-col strips; last 256: w_proj).
__global__ void prep(const float* __restrict__ x, unsigned short* __restrict__ xbf,
                     const float* __restrict__ wa, unsigned short* __restrict__ da,
                     const float* __restrict__ wp, unsigned short* __restrict__ dp) {
  __shared__ float tile[64][65];
  const int t = threadIdx.x;
  const int bid = blockIdx.x;
  if (bid < 4096) {
    int i = bid * 256 + t;
    float4 v = ((const float4*)x)[i];
    ushort4 o;
    o.x = f2bf(v.x); o.y = f2bf(v.y); o.z = f2bf(v.z); o.w = f2bf(v.w);
    ((ushort4*)xbf)[i] = o;
    return;
  }
  int idx = bid - 4096;          // 0..1023
  const int tr = idx & 15;       // 16 row-strips of 64
  int y = idx >> 4;              // 0..63
  const float* src;
  unsigned short* dst;
  int C;
  if (y < 48) { src = wa; dst = da; C = 3072; }
  else        { src = wp; dst = dp; C = 1024; y -= 48; }
  const int tc = y;  // block-uniform
#pragma unroll
  for (int i = 0; i < 16; ++i) {
    int id2 = t + i * 256;
    int lr = id2 >> 6, lc = id2 & 63;
    tile[lr][lc] = src[(size_t)(tr * 64 + lr) * C + tc * 64 + lc];
  }
  __syncthreads();
#pragma unroll
  for (int i = 0; i < 16; ++i) {
    int id2 = t + i * 256;
    int lr = id2 >> 6, lc = id2 & 63;
    dst[(size_t)(tc * 64 + lr) * 1024 + tr * 64 + lc] = f2bf(tile[lc][lr]);
  }
}

// ---------------------------------------------------------------- GEMM ----
template <int KDIM>
__device__ __forceinline__ void gemm_core(const short* __restrict__ A, const short* __restrict__ Bt,
                                          int mbase, int nbase, short* As, short* Bs,
                                          int wm, int wn, int quad, int l16, int t,
                                          f32x4 (&acc)[4][4]) {
  for (int kt = 0; kt < KDIM / 32; ++kt) {
#pragma unroll
    for (int i = 0; i < 2; ++i) {
      int c = t + i * 256;
      int row = c >> 2, c4 = c & 3;
      gld16(A + (size_t)(mbase + row) * KDIM + kt * 32 + c4 * 8, (char*)As + c * 16);
      gld16(Bt + (size_t)(nbase + row) * KDIM + kt * 32 + c4 * 8, (char*)Bs + c * 16);
    }
    __syncthreads();
    short8 af[4], bf[4];
#pragma unroll
    for (int m = 0; m < 4; ++m)
      af[m] = *(const short8*)((const char*)As + (wm + m * 16 + l16) * 64 + quad * 16);
#pragma unroll
    for (int n = 0; n < 4; ++n)
      bf[n] = *(const short8*)((const char*)Bs + (wn + n * 16 + l16) * 64 + quad * 16);
#pragma unroll
    for (int m = 0; m < 4; ++m)
#pragma unroll
      for (int n = 0; n < 4; ++n)
        acc[m][n] = mfma_bf16(af[m], bf[n], acc[m][n]);
    __syncthreads();
  }
}

// Unified QKV GEMM: grid (32, 24) = 768 blocks (3/CU). nbase<2048 -> Q/K scatter
// (Q pre-scaled by QSCALE for log2-domain flash); nbase>=2048 -> V path with
// LDS-transpose epilogue emitting V' tau64-permuted [bh][d][2048]:
// stored pos (per 64-block) = 32*s5 + 8*((s>>2)&3) + 4*s4 + (s&3).
// tau64 matches flash's in-register P packing (swapped-QK S^T frags pack
// in-lane into PV A-operands with NO cross-lane moves).
__global__ __launch_bounds__(256, 2) void gemm_qkv(
    const short* __restrict__ A, const short* __restrict__ Bt, const float* __restrict__ bias,
    unsigned short* __restrict__ q, unsigned short* __restrict__ k,
    unsigned short* __restrict__ vt) {
  __shared__ __align__(16) char smem[17408];
  short* As = (short*)smem;
  short* Bs = (short*)(smem + 8192);
  unsigned short* vlds = (unsigned short*)smem;  // [64 d][136] permuted s (V epilogue)
  const int t = threadIdx.x;
  const int wave = t >> 6, lane = t & 63;
  const int quad = lane >> 4, l16 = lane & 15;
  const int wm = (wave >> 1) * 64, wn = (wave & 1) * 64;
  const int mbase = blockIdx.x * 128, nbase = blockIdx.y * 128;
  f32x4 acc[4][4];
#pragma unroll
  for (int i = 0; i < 4; ++i)
#pragma unroll
    for (int j = 0; j < 4; ++j) acc[i][j] = (f32x4)0.0f;
  gemm_core<1024>(A, Bt, mbase, nbase, As, Bs, wm, wn, quad, l16, t, acc);

  if (nbase < 2048) {
    // ---- Q/K scatter epilogue ----
#pragma unroll
    for (int n = 0; n < 4; ++n) {
      int col = nbase + wn + n * 16 + l16;      // 0..2047
      float bc = bias[col];
      int which = col >> 10, rem = col & 1023;  // wave-uniform per n
      int h = rem >> 6, d = rem & 63;
      unsigned short* dst = which ? k : q;
      float scale = which ? 1.0f : QSCALE;
#pragma unroll
      for (int m = 0; m < 4; ++m) {
#pragma unroll
        for (int r = 0; r < 4; ++r) {
          int row = mbase + wm + m * 16 + quad * 4 + r;
          int b = row >> 11, s = row & 2047;
          dst[(((size_t)(b * 16 + h)) * 2048 + s) * 64 + d] = f2bf((acc[m][n][r] + bc) * scale);
        }
      }
    }
  } else {
    // ---- V transpose epilogue: tau64 per 64-block ----
    const int b = mbase >> 11, s0 = mbase & 2047;
    const int vcb = nbase - 2048;  // 0..895, v-column base
    __syncthreads();               // hard fence before vlds reuses the GEMM stage region
#pragma unroll
    for (int half = 0; half < 2; ++half) {
      if (wn == half * 64) {
#pragma unroll
        for (int n = 0; n < 4; ++n) {
          int col_l = n * 16 + l16;  // d 0..63
          float bc = bias[nbase + half * 64 + col_l];
#pragma unroll
          for (int m = 0; m < 4; ++m)
#pragma unroll
            for (int r = 0; r < 4; ++r) {
              int row_l = wm + m * 16 + quad * 4 + r;  // s_local 0..127
              int idx = (row_l & 64) + ((row_l >> 5) & 1) * 32 +
                        ((row_l >> 2) & 3) * 8 + ((row_l >> 4) & 1) * 4 + (row_l & 3);
              vlds[col_l * 136 + idx] = f2bf(acc[m][n][r] + bc);
            }
        }
      }
      __syncthreads();
      int h = (vcb + half * 64) >> 6;  // head 0..15
      size_t obase = ((size_t)(b * 16 + h)) * 64 * 2048;
#pragma unroll
      for (int i = 0; i < 4; ++i) {
        int c = t + i * 256;
        int d_l = c >> 4, c16 = c & 15;
        short8 v = *(const short8*)&vlds[d_l * 136 + c16 * 8];
        *(short8*)&vt[obase + (size_t)d_l * 2048 + s0 + c16 * 8] = v;
      }
      __syncthreads();
    }
  }
}

// Proj: 64x128 tiles, grid (64,8) = 512 blocks (2/CU) — R8-proven correct+faster.
__global__ __launch_bounds__(256, 2) void gemm_proj(
    const short* __restrict__ A, const short* __restrict__ Bt, const float* __restrict__ bias,
    float* __restrict__ out) {
  __shared__ __align__(16) short As[64 * 32];
  __shared__ __align__(16) short Bs[128 * 32];
  const int t = threadIdx.x;
  const int wave = t >> 6, lane = t & 63;
  const int quad = lane >> 4, l16 = lane & 15;
  const int wm = (wave >> 1) * 32, wn = (wave & 1) * 64;
  const int mbase = blockIdx.x * 64, nbase = blockIdx.y * 128;
  f32x4 acc[2][4];
#pragma unroll
  for (int i = 0; i < 2; ++i)
#pragma unroll
    for (int j = 0; j < 4; ++j) acc[i][j] = (f32x4)0.0f;
  for (int kt = 0; kt < 32; ++kt) {
    {  // A: 64 rows x 4 chunks = 256 chunks, 1/thread
      int row = t >> 2, c4 = t & 3;
      gld16(A + (size_t)(mbase + row) * 1024 + kt * 32 + c4 * 8, (char*)As + t * 16);
    }
#pragma unroll
    for (int i = 0; i < 2; ++i) {  // B: 128 rows x 4 chunks = 512 chunks, 2/thread
      int c = t + i * 256;
      int row = c >> 2, c4 = c & 3;
      gld16(Bt + (size_t)(nbase + row) * 1024 + kt * 32 + c4 * 8, (char*)Bs + c * 16);
    }
    __syncthreads();
    short8 af[2], bf[4];
#pragma unroll
    for (int m = 0; m < 2; ++m)
      af[m] = *(const short8*)((const char*)As + (wm + m * 16 + l16) * 64 + quad * 16);
#pragma unroll
    for (int n = 0; n < 4; ++n)
      bf[n] = *(const short8*)((const char*)Bs + (wn + n * 16 + l16) * 64 + quad * 16);
#pragma unroll
    for (int m = 0; m < 2; ++m)
#pragma unroll
      for (int n = 0; n < 4; ++n)
        acc[m][n] = mfma_bf16(af[m], bf[n], acc[m][n]);
    __syncthreads();
  }
#pragma unroll
  for (int n = 0; n < 4; ++n) {
    int col = nbase + wn + n * 16 + l16;
    float bc = bias[col];
#pragma unroll
    for (int m = 0; m < 2; ++m)
#pragma unroll
      for (int r = 0; r < 4; ++r) {
        int row = mbase + wm + m * 16 + quad * 4 + r;
        out[(size_t)row * 1024 + col] = acc[m][n][r] + bc;
      }
  }
}

// ---------------------------------------------------------------- flash ----
// R16: 3-buffer 2-ahead pipeline with counted vmcnt (T4). R15 post-mortem:
// address-math removal was neutral -> the serializer is the per-kt
// __syncthreads() vmcnt(0) drain of loads issued only ~600cy earlier (any L2
// miss exposes 300-900cy x32 to the whole block at 2 waves/SIMD).
//  * K/V x3 buffers (48K LDS). stage(kt+2) issued during iter kt.
//  * Top of iter kt: s_waitcnt vmcnt(4) (stage(kt+1) stays IN FLIGHT across
//    the barrier) + raw s_barrier + sched_barrier(0) (rule-18 hoist guard).
//    The wait targets loads issued TWO iterations (~1200cy) ago -> ~0 stall.
//  * mask float4 loads issued BEFORE stage gld16s, sched_barrier(0) between
//    (keeps mask older in vmcnt queue -> softmax's auto-wait is vmcnt(4),
//    never a stage drain).
//  * Buffer reuse distance 2 (<3 bufs), one barrier between last-read and
//    next-write: reads(kt-1) < barrier(kt) < stage(kt+2) issue. Race-safe.
//  * Tail: kt=30 no stage (vmcnt(4)); kt=31 vmcnt(0).
// Everything else = R14/R15: swapped-QK in-register softmax (no P in LDS),
// tau64 V', KVBLK=64, Br=128, grid (32,16), 1 barrier/kt.
__global__ __launch_bounds__(256, 2) void flash_attn(
    const short* __restrict__ Qg, const short* __restrict__ Kg, const short* __restrict__ Vtg,
    const float* __restrict__ mask, unsigned short* __restrict__ ctx) {
  __shared__ __align__(16) unsigned char smem[49152];
  // K bufs: [0,24576) three 8K; V bufs: [24576,49152) three 8K
  const int t = threadIdx.x;  // 0..255
  const int wave = t >> 6, lane = t & 63;
  const int quad = lane >> 4, l16 = lane & 15;
  const int bh = blockIdx.x, b = bh >> 4, h = bh & 15;
  const int qbase = blockIdx.y * 128;
  const size_t bh_off = (size_t)bh * 2048 * 64;

  // ---- Q stage (16 KB, overlaps Kbuf0/Kbuf1 region), then to registers ----
#pragma unroll
  for (int i = 0; i < 4; ++i) {
    int c = t + i * 256;
    int row = c >> 3, col = c & 7;
    gld16(Qg + bh_off + (size_t)(qbase + row) * 64 + (col ^ (row & 7)) * 8,
          (char*)smem + c * 16);
  }
  __syncthreads();
  short8 qf[2][2];  // [m-frag][ks]
#pragma unroll
  for (int mf = 0; mf < 2; ++mf)
#pragma unroll
    for (int ks = 0; ks < 2; ++ks) {
      int row = wave * 32 + mf * 16 + l16;
      qf[mf][ks] = *(const short8*)((const char*)smem +
                                    (row * 8 + ((ks * 4 + quad) ^ (l16 & 7))) * 16);
    }
  __syncthreads();  // all waves done reading Q before K staging reuses region

  // ---- loop-invariant LDS byte offsets (VGPR-resident) ----
  int koff[2][4];  // [ks][n]
#pragma unroll
  for (int ks = 0; ks < 2; ++ks)
#pragma unroll
    for (int n = 0; n < 4; ++n) {
      int row = n * 16 + l16;
      koff[ks][n] = (row * 8 + ((ks * 4 + quad) ^ (l16 & 7))) * 16;
    }
  int voff[2][4];  // [ks][db]
#pragma unroll
  for (int ks = 0; ks < 2; ++ks)
#pragma unroll
    for (int db = 0; db < 4; ++db) {
      int d = db * 16 + l16;
      voff[ks][db] = d * 128 + (((ks * 4 + quad) ^ (d & 7)) * 16);
    }

  // ---- staging source pointers (increment by constants each stage) ----
  const short* kgp[2];
  const short* vgp[2];
#pragma unroll
  for (int i = 0; i < 2; ++i) {
    int c = t + i * 256;
    int row = c >> 3, col = c & 7;
    kgp[i] = Kg + bh_off + (size_t)row * 64 + (col ^ (row & 7)) * 8;
    vgp[i] = Vtg + ((size_t)bh * 64 + row) * 2048 + (col ^ (row & 7)) * 8;
  }
  const float* mpt = mask + b * 2048 + quad * 4;

  auto stage_to = [&](char* kd, char* vd) {
#pragma unroll
    for (int i = 0; i < 2; ++i) {
      gld16(kgp[i], kd + (t + i * 256) * 16);
      gld16(vgp[i], vd + (t + i * 256) * 16);
    }
    kgp[0] += 4096; kgp[1] += 4096;  // 64 rows x 64 shorts
    vgp[0] += 64;   vgp[1] += 64;    // 64 shorts along s
  };

  f32x4 O[2][4];
  float l_part[2];
#pragma unroll
  for (int mf = 0; mf < 2; ++mf)
#pragma unroll
    for (int d = 0; d < 4; ++d) O[mf][d] = (f32x4)0.0f;
  l_part[0] = 0.0f;
  l_part[1] = 0.0f;

  char* const KB[3] = {(char*)smem, (char*)smem + 8192, (char*)smem + 16384};
  char* const VB[3] = {(char*)smem + 24576, (char*)smem + 32768, (char*)smem + 40960};

  // iteration body: barrier (caller does the vmcnt wait), mask, optional
  // stage(kt+2), QK, in-register softmax, PV. No trailing barrier.
  auto iter_body = [&](const char* Kc, const char* Vc, char* ksd, char* vsd,
                       bool doStage) {
    __builtin_amdgcn_s_barrier();
    __builtin_amdgcn_sched_barrier(0);  // no ds_read of buf[kt] above barrier

    float4 mq[4];
#pragma unroll
    for (int n = 0; n < 4; ++n) mq[n] = *(const float4*)(mpt + n * 16);
    mpt += 64;
    __builtin_amdgcn_sched_barrier(0);  // mask loads stay OLDER than stage

    if (doStage) stage_to(ksd, vsd);

    // ---- S^T = K @ Q^T (log2 domain); kf feeds BOTH m-frags ----
    f32x4 sa[2][4];
    __builtin_amdgcn_s_setprio(1);
#pragma unroll
    for (int n = 0; n < 4; ++n) {
      short8 kf = *(const short8*)(Kc + koff[0][n]);
      sa[0][n] = mfma_bf16(kf, qf[0][0], (f32x4)0.0f);
      sa[1][n] = mfma_bf16(kf, qf[1][0], (f32x4)0.0f);
    }
#pragma unroll
    for (int n = 0; n < 4; ++n) {
      short8 kf = *(const short8*)(Kc + koff[1][n]);
      sa[0][n] = mfma_bf16(kf, qf[0][1], sa[0][n]);
      sa[1][n] = mfma_bf16(kf, qf[1][1], sa[1][n]);
    }
    __builtin_amdgcn_s_setprio(0);

    // ---- softmax fully in-register: lane owns q=l16, k = n*16+quad*4+r ----
    short8 pa[2][2];
#pragma unroll
    for (int mf = 0; mf < 2; ++mf) {
      float rs = 0.0f;
#pragma unroll
      for (int n = 0; n < 4; ++n) {
#pragma unroll
        for (int r = 0; r < 4; ++r) {
          float p = __builtin_amdgcn_exp2f(__builtin_fmaf(mq[n][r], L2E, sa[mf][n][r]));
          rs += p;
          pa[mf][n >> 1][(n & 1) * 4 + r] = (short)f2bf(p);
        }
      }
      l_part[mf] += rs;
    }

    // ---- O += P @ V' (vf feeds BOTH m-frags) ----
    __builtin_amdgcn_s_setprio(1);
#pragma unroll
    for (int ks = 0; ks < 2; ++ks) {
#pragma unroll
      for (int db = 0; db < 4; ++db) {
        short8 vf = *(const short8*)(Vc + voff[ks][db]);
        O[0][db] = mfma_bf16(pa[0][ks], vf, O[0][db]);
        O[1][db] = mfma_bf16(pa[1][ks], vf, O[1][db]);
      }
    }
    __builtin_amdgcn_s_setprio(0);
  };

  // prologue: stage kt=0 and kt=1 (8 vmem ops outstanding)
  stage_to(KB[0], VB[0]);
  stage_to(KB[1], VB[1]);

#define VMW4 asm volatile("s_waitcnt vmcnt(4)" ::: "memory")
#define VMW0 asm volatile("s_waitcnt vmcnt(0)" ::: "memory")

#pragma unroll 1
  for (int kt3 = 0; kt3 < 30; kt3 += 3) {
    VMW4; iter_body(KB[0], VB[0], KB[2], VB[2], true);
    VMW4; iter_body(KB[1], VB[1], KB[0], VB[0], true);
    VMW4; iter_body(KB[2], VB[2], KB[1], VB[1], true);
  }
  // kt = 30 (buf 0, stage(32) doesn't exist), kt = 31 (buf 1, full drain)
  VMW4; iter_body(KB[0], VB[0], nullptr, nullptr, false);
  VMW0; iter_body(KB[1], VB[1], nullptr, nullptr, false);

#undef VMW4
#undef VMW0

  // ---- l reduce: sum over quads (lane bits 4,5), then transpose to O layout ----
  float lr[2];
#pragma unroll
  for (int mf = 0; mf < 2; ++mf) {
    float l = l_part[mf];
    l += __shfl_xor(l, 16);
    l += __shfl_xor(l, 32);
    lr[mf] = l;  // valid for q = l16 (all quads hold it)
  }
#pragma unroll
  for (int mf = 0; mf < 2; ++mf) {
#pragma unroll
    for (int r = 0; r < 4; ++r) {
      float lq = __shfl(lr[mf], quad * 4 + r);  // l for q-local = quad*4+r
      float inv = 1.0f / lq;
      int s = qbase + wave * 32 + mf * 16 + quad * 4 + r;
      size_t o = ((size_t)b * 2048 + s) * 1024 + h * 64;
#pragma unroll
      for (int db = 0; db < 4; ++db)
        ctx[o + db * 16 + l16] = f2bf(O[mf][db][r] * inv);
    }
  }
}

// ---------------------------------------------------------------- launch ----
extern "C" void kernel_launch(void* const* d_in, const int* in_sizes, int n_in,
                              void* d_out, int out_size, void* d_ws, size_t ws_size,
                              hipStream_t stream) {
  const float* x      = (const float*)d_in[0];
  const float* mask   = (const float*)d_in[1];
  const float* w_attn = (const float*)d_in[2];
  const float* b_attn = (const float*)d_in[3];
  const float* w_proj = (const float*)d_in[4];
  const float* b_proj = (const float*)d_in[5];
  float* out = (float*)d_out;

  char* ws = (char*)d_ws;
  const size_t MB = 1024 * 1024;
  short*          Xbf    = (short*)(ws);                     // 8 MB, reused as ctx
  short*          Wqkv_t = (short*)(ws + 8 * MB);            // 6 MB
  short*          Wprj_t = (short*)(ws + 14 * MB);           // 2 MB
  unsigned short* Qb     = (unsigned short*)(ws + 16 * MB);  // 8 MB
  unsigned short* Kb     = (unsigned short*)(ws + 24 * MB);  // 8 MB
  unsigned short* Vtb    = (unsigned short*)(ws + 32 * MB);  // 8 MB
  unsigned short* ctx    = (unsigned short*)Xbf;

  prep<<<5120, 256, 0, stream>>>(x, (unsigned short*)Xbf,
                                 w_attn, (unsigned short*)Wqkv_t,
                                 w_proj, (unsigned short*)Wprj_t);
  gemm_qkv<<<dim3(32, 24), 256, 0, stream>>>(Xbf, Wqkv_t, b_attn, Qb, Kb, Vtb);
  flash_attn<<<dim3(32, 16), 256, 0, stream>>>((const short*)Qb, (const short*)Kb,
                                               (const short*)Vtb, mask, ctx);
  gemm_proj<<<dim3(64, 8), 256, 0, stream>>>((const short*)ctx, Wprj_t, b_proj, out);
}

// Round 7
// 178.729 us; speedup vs baseline: 1.0136x; 1.0003x over previous
//
#include <hip/hip_runtime.h>
#include <hip/hip_bf16.h>

typedef __attribute__((ext_vector_type(8))) short short8;
typedef __attribute__((ext_vector_type(4))) float f32x4;

// __float2bfloat16 emits a single HW cvt op on gfx950 (R8: bit-trick regressed).
__device__ __forceinline__ unsigned short f2bf(float f) {
  union { __hip_bfloat16 h; unsigned short u; } cv;
  cv.h = __float2bfloat16(f);
  return cv.u;
}

__device__ __forceinline__ void gld16(const void* g, void* l) {
  __builtin_amdgcn_global_load_lds(
      (const __attribute__((address_space(1))) unsigned int*)g,
      (__attribute__((address_space(3))) unsigned int*)l, 16, 0, 0);
}

__device__ __forceinline__ f32x4 mfma_bf16(short8 a, short8 b, f32x4 c) {
  return __builtin_amdgcn_mfma_f32_16x16x32_bf16(a, b, c, 0, 0, 0);
}

#define QSCALE 0.18033688011112042f  /* 0.125 * log2(e): scores in log2 domain */
#define L2E    1.4426950408889634f

// ---------------------------------------------------------------- prep ----
// One launch: blocks [0,4096) cast X fp32->bf16; blocks [4096,5120) transpose
// weights (first 768: w_attn 64-col strips; last 256: w_proj).
__global__ void prep(const float* __restrict__ x, unsigned short* __restrict__ xbf,
                     const float* __restrict__ wa, unsigned short* __restrict__ da,
                     const float* __restrict__ wp, unsigned short* __restrict__ dp) {
  __shared__ float tile[64][65];
  const int t = threadIdx.x;
  const int bid = blockIdx.x;
  if (bid < 4096) {
    int i = bid * 256 + t;
    float4 v = ((const float4*)x)[i];
    ushort4 o;
    o.x = f2bf(v.x); o.y = f2bf(v.y); o.z = f2bf(v.z); o.w = f2bf(v.w);
    ((ushort4*)xbf)[i] = o;
    return;
  }
  int idx = bid - 4096;          // 0..1023
  const int tr = idx & 15;       // 16 row-strips of 64
  int y = idx >> 4;              // 0..63
  const float* src;
  unsigned short* dst;
  int C;
  if (y < 48) { src = wa; dst = da; C = 3072; }
  else        { src = wp; dst = dp; C = 1024; y -= 48; }
  const int tc = y;  // block-uniform
#pragma unroll
  for (int i = 0; i < 16; ++i) {
    int id2 = t + i * 256;
    int lr = id2 >> 6, lc = id2 & 63;
    tile[lr][lc] = src[(size_t)(tr * 64 + lr) * C + tc * 64 + lc];
  }
  __syncthreads();
#pragma unroll
  for (int i = 0; i < 16; ++i) {
    int id2 = t + i * 256;
    int lr = id2 >> 6, lc = id2 & 63;
    dst[(size_t)(tc * 64 + lr) * 1024 + tr * 64 + lc] = f2bf(tile[lc][lr]);
  }
}

// ---------------------------------------------------------------- GEMM ----
template <int KDIM>
__device__ __forceinline__ void gemm_core(const short* __restrict__ A, const short* __restrict__ Bt,
                                          int mbase, int nbase, short* As, short* Bs,
                                          int wm, int wn, int quad, int l16, int t,
                                          f32x4 (&acc)[4][4]) {
  for (int kt = 0; kt < KDIM / 32; ++kt) {
#pragma unroll
    for (int i = 0; i < 2; ++i) {
      int c = t + i * 256;
      int row = c >> 2, c4 = c & 3;
      gld16(A + (size_t)(mbase + row) * KDIM + kt * 32 + c4 * 8, (char*)As + c * 16);
      gld16(Bt + (size_t)(nbase + row) * KDIM + kt * 32 + c4 * 8, (char*)Bs + c * 16);
    }
    __syncthreads();
    short8 af[4], bf[4];
#pragma unroll
    for (int m = 0; m < 4; ++m)
      af[m] = *(const short8*)((const char*)As + (wm + m * 16 + l16) * 64 + quad * 16);
#pragma unroll
    for (int n = 0; n < 4; ++n)
      bf[n] = *(const short8*)((const char*)Bs + (wn + n * 16 + l16) * 64 + quad * 16);
#pragma unroll
    for (int m = 0; m < 4; ++m)
#pragma unroll
      for (int n = 0; n < 4; ++n)
        acc[m][n] = mfma_bf16(af[m], bf[n], acc[m][n]);
    __syncthreads();
  }
}

// Unified QKV GEMM: grid (32, 24) = 768 blocks (3/CU). nbase<2048 -> Q/K scatter
// (Q pre-scaled by QSCALE for log2-domain flash); nbase>=2048 -> V path with
// LDS-transpose epilogue emitting V' tau64-permuted [bh][d][2048]:
// stored pos (per 64-block) = 32*s5 + 8*((s>>2)&3) + 4*s4 + (s&3).
// tau64 matches flash's in-register P packing (swapped-QK S^T frags pack
// in-lane into PV A-operands with NO cross-lane moves).
__global__ __launch_bounds__(256, 2) void gemm_qkv(
    const short* __restrict__ A, const short* __restrict__ Bt, const float* __restrict__ bias,
    unsigned short* __restrict__ q, unsigned short* __restrict__ k,
    unsigned short* __restrict__ vt) {
  __shared__ __align__(16) char smem[17408];
  short* As = (short*)smem;
  short* Bs = (short*)(smem + 8192);
  unsigned short* vlds = (unsigned short*)smem;  // [64 d][136] permuted s (V epilogue)
  const int t = threadIdx.x;
  const int wave = t >> 6, lane = t & 63;
  const int quad = lane >> 4, l16 = lane & 15;
  const int wm = (wave >> 1) * 64, wn = (wave & 1) * 64;
  const int mbase = blockIdx.x * 128, nbase = blockIdx.y * 128;
  f32x4 acc[4][4];
#pragma unroll
  for (int i = 0; i < 4; ++i)
#pragma unroll
    for (int j = 0; j < 4; ++j) acc[i][j] = (f32x4)0.0f;
  gemm_core<1024>(A, Bt, mbase, nbase, As, Bs, wm, wn, quad, l16, t, acc);

  if (nbase < 2048) {
    // ---- Q/K scatter epilogue ----
#pragma unroll
    for (int n = 0; n < 4; ++n) {
      int col = nbase + wn + n * 16 + l16;      // 0..2047
      float bc = bias[col];
      int which = col >> 10, rem = col & 1023;  // wave-uniform per n
      int h = rem >> 6, d = rem & 63;
      unsigned short* dst = which ? k : q;
      float scale = which ? 1.0f : QSCALE;
#pragma unroll
      for (int m = 0; m < 4; ++m) {
#pragma unroll
        for (int r = 0; r < 4; ++r) {
          int row = mbase + wm + m * 16 + quad * 4 + r;
          int b = row >> 11, s = row & 2047;
          dst[(((size_t)(b * 16 + h)) * 2048 + s) * 64 + d] = f2bf((acc[m][n][r] + bc) * scale);
        }
      }
    }
  } else {
    // ---- V transpose epilogue: tau64 per 64-block ----
    const int b = mbase >> 11, s0 = mbase & 2047;
    const int vcb = nbase - 2048;  // 0..895, v-column base
    __syncthreads();               // hard fence before vlds reuses the GEMM stage region
#pragma unroll
    for (int half = 0; half < 2; ++half) {
      if (wn == half * 64) {
#pragma unroll
        for (int n = 0; n < 4; ++n) {
          int col_l = n * 16 + l16;  // d 0..63
          float bc = bias[nbase + half * 64 + col_l];
#pragma unroll
          for (int m = 0; m < 4; ++m)
#pragma unroll
            for (int r = 0; r < 4; ++r) {
              int row_l = wm + m * 16 + quad * 4 + r;  // s_local 0..127
              int idx = (row_l & 64) + ((row_l >> 5) & 1) * 32 +
                        ((row_l >> 2) & 3) * 8 + ((row_l >> 4) & 1) * 4 + (row_l & 3);
              vlds[col_l * 136 + idx] = f2bf(acc[m][n][r] + bc);
            }
        }
      }
      __syncthreads();
      int h = (vcb + half * 64) >> 6;  // head 0..15
      size_t obase = ((size_t)(b * 16 + h)) * 64 * 2048;
#pragma unroll
      for (int i = 0; i < 4; ++i) {
        int c = t + i * 256;
        int d_l = c >> 4, c16 = c & 15;
        short8 v = *(const short8*)&vlds[d_l * 136 + c16 * 8];
        *(short8*)&vt[obase + (size_t)d_l * 2048 + s0 + c16 * 8] = v;
      }
      __syncthreads();
    }
  }
}

// Proj: 64x128 tiles, grid (64,8) = 512 blocks (2/CU) — R8-proven correct+faster.
__global__ __launch_bounds__(256, 2) void gemm_proj(
    const short* __restrict__ A, const short* __restrict__ Bt, const float* __restrict__ bias,
    float* __restrict__ out) {
  __shared__ __align__(16) short As[64 * 32];
  __shared__ __align__(16) short Bs[128 * 32];
  const int t = threadIdx.x;
  const int wave = t >> 6, lane = t & 63;
  const int quad = lane >> 4, l16 = lane & 15;
  const int wm = (wave >> 1) * 32, wn = (wave & 1) * 64;
  const int mbase = blockIdx.x * 64, nbase = blockIdx.y * 128;
  f32x4 acc[2][4];
#pragma unroll
  for (int i = 0; i < 2; ++i)
#pragma unroll
    for (int j = 0; j < 4; ++j) acc[i][j] = (f32x4)0.0f;
  for (int kt = 0; kt < 32; ++kt) {
    {  // A: 64 rows x 4 chunks = 256 chunks, 1/thread
      int row = t >> 2, c4 = t & 3;
      gld16(A + (size_t)(mbase + row) * 1024 + kt * 32 + c4 * 8, (char*)As + t * 16);
    }
#pragma unroll
    for (int i = 0; i < 2; ++i) {  // B: 128 rows x 4 chunks = 512 chunks, 2/thread
      int c = t + i * 256;
      int row = c >> 2, c4 = c & 3;
      gld16(Bt + (size_t)(nbase + row) * 1024 + kt * 32 + c4 * 8, (char*)Bs + c * 16);
    }
    __syncthreads();
    short8 af[2], bf[4];
#pragma unroll
    for (int m = 0; m < 2; ++m)
      af[m] = *(const short8*)((const char*)As + (wm + m * 16 + l16) * 64 + quad * 16);
#pragma unroll
    for (int n = 0; n < 4; ++n)
      bf[n] = *(const short8*)((const char*)Bs + (wn + n * 16 + l16) * 64 + quad * 16);
#pragma unroll
    for (int m = 0; m < 2; ++m)
#pragma unroll
      for (int n = 0; n < 4; ++n)
        acc[m][n] = mfma_bf16(af[m], bf[n], acc[m][n]);
    __syncthreads();
  }
#pragma unroll
  for (int n = 0; n < 4; ++n) {
    int col = nbase + wn + n * 16 + l16;
    float bc = bias[col];
#pragma unroll
    for (int m = 0; m < 2; ++m)
#pragma unroll
      for (int r = 0; r < 4; ++r) {
        int row = mbase + wm + m * 16 + quad * 4 + r;
        out[(size_t)row * 1024 + col] = acc[m][n][r] + bc;
      }
  }
}

// ---------------------------------------------------------------- flash ----
// R17: intra-wave 2-stage pipeline (T15): QK one tile AHEAD so softmax(kt)
// [VALU] overlaps QK(kt+1) [MFMA] — the pipes are separate HW (m114).
// R16 post-mortem: no pipe saturated (LDS 50%, VALU 39%, MFMA 27%); the bound
// was the wave-serial QK->softmax->PV chain at 2 waves/SIMD in lockstep.
// Structure per body(kt):
//   vmcnt(0)+s_barrier+sched_barrier   (all waited loads are a FULL body old
//                                       -> drain is free; no counted-vmcnt
//                                       bookkeeping vs compiler loads)
//   stage K(kt+2)->buf kt&1, V(kt+1)->buf (kt+1)&1, load mq(kt+1)
//   QK(kt+1)->sa_next [MFMA] ∥ softmax(kt) from sa_cur [VALU]   (independent)
//   PV(kt) from pa, V[kt]   [MFMA, setprio]
// Static double-state saA/saB, mqA/mqB via even/odd bodies (rule #20: no
// runtime-indexed register rotation). Buffer safety: body(kt) writes the
// buffers whose last readers ran pre-barrier in body(kt-1).
// LDS = K dbuf 2x8K + V dbuf 2x8K = 32768. Everything else = R14 lineage:
// swapped-QK in-register softmax (no P in LDS), tau64 V', KVBLK=64, Br=128,
// grid (32,16), 256 thr.
__global__ __launch_bounds__(256, 2) void flash_attn(
    const short* __restrict__ Qg, const short* __restrict__ Kg, const short* __restrict__ Vtg,
    const float* __restrict__ mask, unsigned short* __restrict__ ctx) {
  __shared__ __align__(16) unsigned char smem[32768];
  // K bufs: [0,8K),[8K,16K); V bufs: [16K,24K),[24K,32K)
  const int t = threadIdx.x;  // 0..255
  const int wave = t >> 6, lane = t & 63;
  const int quad = lane >> 4, l16 = lane & 15;
  const int bh = blockIdx.x, b = bh >> 4, h = bh & 15;
  const int qbase = blockIdx.y * 128;
  const size_t bh_off = (size_t)bh * 2048 * 64;

  // ---- Q stage (16 KB = K-dbuf region), then to registers ----
#pragma unroll
  for (int i = 0; i < 4; ++i) {
    int c = t + i * 256;
    int row = c >> 3, col = c & 7;
    gld16(Qg + bh_off + (size_t)(qbase + row) * 64 + (col ^ (row & 7)) * 8,
          (char*)smem + c * 16);
  }
  __syncthreads();
  short8 qf[2][2];  // [m-frag][ks]
#pragma unroll
  for (int mf = 0; mf < 2; ++mf)
#pragma unroll
    for (int ks = 0; ks < 2; ++ks) {
      int row = wave * 32 + mf * 16 + l16;
      qf[mf][ks] = *(const short8*)((const char*)smem +
                                    (row * 8 + ((ks * 4 + quad) ^ (l16 & 7))) * 16);
    }
  __syncthreads();  // all waves done reading Q before K staging reuses region

  // ---- loop-invariant LDS byte offsets (VGPR-resident) ----
  int koff[2][4];  // [ks][n]
#pragma unroll
  for (int ks = 0; ks < 2; ++ks)
#pragma unroll
    for (int n = 0; n < 4; ++n) {
      int row = n * 16 + l16;
      koff[ks][n] = (row * 8 + ((ks * 4 + quad) ^ (l16 & 7))) * 16;
    }
  int voff[2][4];  // [ks][db]
#pragma unroll
  for (int ks = 0; ks < 2; ++ks)
#pragma unroll
    for (int db = 0; db < 4; ++db) {
      int d = db * 16 + l16;
      voff[ks][db] = d * 128 + (((ks * 4 + quad) ^ (d & 7)) * 16);
    }

  // ---- staging source pointers (increment by constants each stage) ----
  const short* kgp[2];
  const short* vgp[2];
#pragma unroll
  for (int i = 0; i < 2; ++i) {
    int c = t + i * 256;
    int row = c >> 3, col = c & 7;
    kgp[i] = Kg + bh_off + (size_t)row * 64 + (col ^ (row & 7)) * 8;
    vgp[i] = Vtg + ((size_t)bh * 64 + row) * 2048 + (col ^ (row & 7)) * 8;
  }
  const float* mpt = mask + b * 2048 + quad * 4;

  auto stage_k = [&](char* kd) {
#pragma unroll
    for (int i = 0; i < 2; ++i) gld16(kgp[i], kd + (t + i * 256) * 16);
    kgp[0] += 4096; kgp[1] += 4096;  // 64 rows x 64 shorts
  };
  auto stage_v = [&](char* vd) {
#pragma unroll
    for (int i = 0; i < 2; ++i) gld16(vgp[i], vd + (t + i * 256) * 16);
    vgp[0] += 64; vgp[1] += 64;      // 64 shorts along s
  };

  f32x4 O[2][4];
  float l_part[2];
#pragma unroll
  for (int mf = 0; mf < 2; ++mf)
#pragma unroll
    for (int d = 0; d < 4; ++d) O[mf][d] = (f32x4)0.0f;
  l_part[0] = 0.0f;
  l_part[1] = 0.0f;

  f32x4 saA[2][4], saB[2][4];
  float4 mqA[4], mqB[4];
  short8 pa[2][2];

  auto qk = [&](const char* Kc, f32x4 (&sa)[2][4]) {
#pragma unroll
    for (int n = 0; n < 4; ++n) {
      short8 kf = *(const short8*)(Kc + koff[0][n]);
      sa[0][n] = mfma_bf16(kf, qf[0][0], (f32x4)0.0f);
      sa[1][n] = mfma_bf16(kf, qf[1][0], (f32x4)0.0f);
    }
#pragma unroll
    for (int n = 0; n < 4; ++n) {
      short8 kf = *(const short8*)(Kc + koff[1][n]);
      sa[0][n] = mfma_bf16(kf, qf[0][1], sa[0][n]);
      sa[1][n] = mfma_bf16(kf, qf[1][1], sa[1][n]);
    }
  };
  auto sm = [&](f32x4 (&sa)[2][4], float4 (&mq)[4]) {
#pragma unroll
    for (int mf = 0; mf < 2; ++mf) {
      float rs = 0.0f;
#pragma unroll
      for (int n = 0; n < 4; ++n) {
#pragma unroll
        for (int r = 0; r < 4; ++r) {
          float p = __builtin_amdgcn_exp2f(__builtin_fmaf(mq[n][r], L2E, sa[mf][n][r]));
          rs += p;
          pa[mf][n >> 1][(n & 1) * 4 + r] = (short)f2bf(p);
        }
      }
      l_part[mf] += rs;
    }
  };
  auto pv = [&](const char* Vc) {
    __builtin_amdgcn_s_setprio(1);
#pragma unroll
    for (int ks = 0; ks < 2; ++ks) {
#pragma unroll
      for (int db = 0; db < 4; ++db) {
        short8 vf = *(const short8*)(Vc + voff[ks][db]);
        O[0][db] = mfma_bf16(pa[0][ks], vf, O[0][db]);
        O[1][db] = mfma_bf16(pa[1][ks], vf, O[1][db]);
      }
    }
    __builtin_amdgcn_s_setprio(0);
  };

  char* const KB0 = (char*)smem;
  char* const KB1 = (char*)smem + 8192;
  char* const VB0 = (char*)smem + 16384;
  char* const VB1 = (char*)smem + 24576;

  // body(kt): mode 2 = full; 1 = no K-stage (kt=30); 0 = tail (kt=31)
  auto body = [&](const char* Kn, const char* Vc, char* kst, char* vst,
                  f32x4 (&sac)[2][4], f32x4 (&san)[2][4],
                  float4 (&mqc)[4], float4 (&mqn)[4], int mode) {
    asm volatile("s_waitcnt vmcnt(0)" ::: "memory");
    __builtin_amdgcn_s_barrier();
    __builtin_amdgcn_sched_barrier(0);  // no LDS access hoists above the barrier
    if (mode == 2) stage_k(kst);
    if (mode >= 1) {
      stage_v(vst);
#pragma unroll
      for (int n = 0; n < 4; ++n) mqn[n] = *(const float4*)(mpt + n * 16);
      mpt += 64;
      qk(Kn, san);  // MFMA cluster — independent of sm(sac) below
    }
    sm(sac, mqc);   // VALU cluster — overlaps qk by scheduler
    pv(Vc);
  };

  // ---- prologue: stage K0->KB0, V0->VB0, K1->KB1; mq0; drain; QK(0) ----
  stage_k(KB0);
  stage_v(VB0);
  stage_k(KB1);
#pragma unroll
  for (int n = 0; n < 4; ++n) mqA[n] = *(const float4*)(mpt + n * 16);
  mpt += 64;
  asm volatile("s_waitcnt vmcnt(0)" ::: "memory");
  __builtin_amdgcn_s_barrier();
  __builtin_amdgcn_sched_barrier(0);
  qk(KB0, saA);

  // ---- main loop: bodies kt = 0..29 (QK runs one ahead) ----
#pragma unroll 1
  for (int kt = 0; kt < 30; kt += 2) {
    body(KB1, VB0, KB0, VB1, saA, saB, mqA, mqB, 2);  // even: K[kt+1]=B1, V[kt]=B0
    body(KB0, VB1, KB1, VB0, saB, saA, mqB, mqA, 2);  // odd:  K[kt+2]=B0, V[kt+1]=B1
  }
  // kt=30: QK(31) from KB1, V[30]=VB0, stage V(31)->VB1; no K stage
  body(KB1, VB0, nullptr, VB1, saA, saB, mqA, mqB, 1);
  // kt=31: softmax(saB)+PV only, V[31]=VB1
  body(nullptr, VB1, nullptr, nullptr, saB, saA, mqB, mqA, 0);

  // ---- l reduce: sum over quads (lane bits 4,5), then transpose to O layout ----
  float lr[2];
#pragma unroll
  for (int mf = 0; mf < 2; ++mf) {
    float l = l_part[mf];
    l += __shfl_xor(l, 16);
    l += __shfl_xor(l, 32);
    lr[mf] = l;  // valid for q = l16 (all quads hold it)
  }
#pragma unroll
  for (int mf = 0; mf < 2; ++mf) {
#pragma unroll
    for (int r = 0; r < 4; ++r) {
      float lq = __shfl(lr[mf], quad * 4 + r);  // l for q-local = quad*4+r
      float inv = 1.0f / lq;
      int s = qbase + wave * 32 + mf * 16 + quad * 4 + r;
      size_t o = ((size_t)b * 2048 + s) * 1024 + h * 64;
#pragma unroll
      for (int db = 0; db < 4; ++db)
        ctx[o + db * 16 + l16] = f2bf(O[mf][db][r] * inv);
    }
  }
}

// ---------------------------------------------------------------- launch ----
extern "C" void kernel_launch(void* const* d_in, const int* in_sizes, int n_in,
                              void* d_out, int out_size, void* d_ws, size_t ws_size,
                              hipStream_t stream) {
  const float* x      = (const float*)d_in[0];
  const float* mask   = (const float*)d_in[1];
  const float* w_attn = (const float*)d_in[2];
  const float* b_attn = (const float*)d_in[3];
  const float* w_proj = (const float*)d_in[4];
  const float* b_proj = (const float*)d_in[5];
  float* out = (float*)d_out;

  char* ws = (char*)d_ws;
  const size_t MB = 1024 * 1024;
  short*          Xbf    = (short*)(ws);                     // 8 MB, reused as ctx
  short*          Wqkv_t = (short*)(ws + 8 * MB);            // 6 MB
  short*          Wprj_t = (short*)(ws + 14 * MB);           // 2 MB
  unsigned short* Qb     = (unsigned short*)(ws + 16 * MB);  // 8 MB
  unsigned short* Kb     = (unsigned short*)(ws + 24 * MB);  // 8 MB
  unsigned short* Vtb    = (unsigned short*)(ws + 32 * MB);  // 8 MB
  unsigned short* ctx    = (unsigned short*)Xbf;

  prep<<<5120, 256, 0, stream>>>(x, (unsigned short*)Xbf,
                                 w_attn, (unsigned short*)Wqkv_t,
                                 w_proj, (unsigned short*)Wprj_t);
  gemm_qkv<<<dim3(32, 24), 256, 0, stream>>>(Xbf, Wqkv_t, b_attn, Qb, Kb, Vtb);
  flash_attn<<<dim3(32, 16), 256, 0, stream>>>((const short*)Qb, (const short*)Kb,
                                               (const short*)Vtb, mask, ctx);
  gemm_proj<<<dim3(64, 8), 256, 0, stream>>>((const short*)ctx, Wprj_t, b_proj, out);
}